// Round 5
// baseline (942.698 us; speedup 1.0000x reference)
//
#include <hip/hip_runtime.h>
#include <hip/hip_bf16.h>

#define D 256        // IN_DIM == HID
#define ED 64        // EDGE_DIM
#define LN_EPS 1e-5f

typedef __attribute__((ext_vector_type(8))) short short8;
typedef __attribute__((ext_vector_type(4))) short short4v;
typedef __attribute__((ext_vector_type(4))) float f32x4;

__device__ __forceinline__ short bf16b(float f) {
    return __builtin_bit_cast(short, __float2bfloat16(f));
}
__device__ __forceinline__ float bf2f(short s) {
    unsigned u = ((unsigned)(unsigned short)s) << 16;
    return __builtin_bit_cast(float, u);
}

__device__ __forceinline__ short8 pack8(float4 f0, float4 f1) {
    short8 r;
    r[0] = bf16b(f0.x); r[1] = bf16b(f0.y); r[2] = bf16b(f0.z); r[3] = bf16b(f0.w);
    r[4] = bf16b(f1.x); r[5] = bf16b(f1.y); r[6] = bf16b(f1.z); r[7] = bf16b(f1.w);
    return r;
}

// LDS-only barrier: waits LDS ops, does NOT drain vmcnt (in-flight global
// loads survive). sched_barrier(0) fences compiler motion (rule #18).
__device__ __forceinline__ void lds_barrier() {
    asm volatile("s_waitcnt lgkmcnt(0)" ::: "memory");
    __builtin_amdgcn_s_barrier();
    __builtin_amdgcn_sched_barrier(0);
}

// ---------------- prep: transpose weights to bf16 ----------------
__global__ __launch_bounds__(256) void prep_weights(
    const float* __restrict__ We, const float* __restrict__ W1,
    const float* __restrict__ W2,
    short* __restrict__ Wet, short* __restrict__ W1t, short* __restrict__ W2t) {
    int t = blockIdx.x * 256 + threadIdx.x;
    if (t < D * ED) {
        int n = t >> 6, k = t & (ED - 1);
        Wet[t] = bf16b(We[k * D + n]);
    }
    if (t < D * D) {
        int n = t >> 8, k = t & (D - 1);
        W1t[t] = bf16b(W1[k * D + n]);
        W2t[t] = bf16b(W2[k * D + n]);
    }
}

// cast x (f32) -> xb (bf16), vectorized
__global__ __launch_bounds__(256) void cast_x(
    const float* __restrict__ x, short* __restrict__ xb, int n4) {
    int t = blockIdx.x * 256 + threadIdx.x;
    if (t < n4) {
        float4 v = ((const float4*)x)[t];
        short4v s;
        s[0] = bf16b(v.x); s[1] = bf16b(v.y); s[2] = bf16b(v.z); s[3] = bf16b(v.w);
        ((short4v*)xb)[t] = s;
    }
}

// ---------------- CSR build ----------------
__global__ __launch_bounds__(256) void hist_kernel(
    const int* __restrict__ dst, int* __restrict__ counts, int E) {
    int t = blockIdx.x * 256 + threadIdx.x;
    if (t < E) atomicAdd(&counts[dst[t]], 1);
}

__global__ __launch_bounds__(256) void scan_block(
    const int* __restrict__ in, int* __restrict__ out, int* __restrict__ bsum, int n) {
    int t = threadIdx.x;
    int g = blockIdx.x * 256 + t;
    int v = (g < n) ? in[g] : 0;
    int lane = t & 63, w = t >> 6;
    int xs = v;
#pragma unroll
    for (int d2 = 1; d2 < 64; d2 <<= 1) {
        int y = __shfl_up(xs, d2, 64);
        if (lane >= d2) xs += y;
    }
    __shared__ int wsums[4];
    if (lane == 63) wsums[w] = xs;
    __syncthreads();
    int addv = 0;
    for (int i = 0; i < w; i++) addv += wsums[i];
    if (g < n) out[g] = xs - v + addv;          // exclusive
    if (t == 255 && bsum != nullptr) bsum[blockIdx.x] = xs + addv;  // total
}

__global__ __launch_bounds__(256) void scan_add(
    int* __restrict__ offs, const int* __restrict__ bofs,
    int* __restrict__ cursor, int n, int Nn) {
    int g = blockIdx.x * 256 + threadIdx.x;
    if (g < n) {
        int v = offs[g] + bofs[blockIdx.x];
        offs[g] = v;
        if (g < Nn) cursor[g] = v;
    }
}

__global__ __launch_bounds__(256) void scatter_edges(
    const int* __restrict__ src, const int* __restrict__ dst,
    int* __restrict__ cursor, int* __restrict__ perm,
    int* __restrict__ srcP, int* __restrict__ dstP, int E) {
    int t = blockIdx.x * 256 + threadIdx.x;
    if (t < E) {
        int d = dst[t];
        int p = atomicAdd(&cursor[d], 1);
        perm[p] = t;
        srcP[p] = src[t];
        dstP[p] = d;
    }
}

// ---------- fused edge GEMM + segmented aggregation (v7b, pipelined) ----------
// Persistent blocks grid-stride over 64-edge tiles. Per iteration:
//   * xb[src] rows DMA'd to LDS via global_load_lds (source-pre-swizzled,
//     byte ^= (row&7)<<4, so the unpadded 32KB tile is conflict-free)
//   * ea for tile t+1 prefetched into regs; stays in flight across the two
//     lgkm-only barriers (only the __syncthreads after DMA drains vmcnt)
//   * MFMA msg + in-place relu(msg+be+x) epilogue; Phase D 64-row segmented
//     column scan (flush: store if segment contained in tile, else atomic).
__global__ __launch_bounds__(256, 4) void fused_edge(
    const float* __restrict__ ea, const int* __restrict__ perm,
    const int* __restrict__ srcP, const int* __restrict__ dstP,
    const int* __restrict__ offs, const short* __restrict__ Wet,
    const float* __restrict__ be, const short* __restrict__ xb,
    float* __restrict__ aggr, int E, int ntiles) {
    __shared__ __attribute__((aligned(16))) short tile[64 * 256];  // 32KB linear (swizzled)
    __shared__ int smeta[2][2][64];   // [buf][0=src,1=dst][row]
    const int t    = threadIdx.x;
    const int lane = t & 63;
    const int w    = t >> 6;
    const int q    = lane >> 4;
    const int ln   = lane & 15;
    const int stride = gridDim.x;

    int tb = blockIdx.x;
    int bufc = 0;

    // ---- prologue: meta(t0) + ea(t0) prefetch ----
    if (t < 64) {
        long p = (long)tb * 64 + t;
        long pc = (p < (long)E) ? p : (long)E - 1;
        smeta[0][0][t] = srcP[pc];
        smeta[0][1][t] = (p < (long)E) ? dstP[pc] : -1;
    }
    float4 f0, f1, f2, f3;
    {
        long ep = (long)tb * 64 + w * 16 + ln;
        if (ep >= (long)E) ep = (long)E - 1;
        int eid = perm[ep];
        const float* ear = ea + (long)eid * ED + q * 8;
        f0 = *(const float4*)(ear);
        f1 = *(const float4*)(ear + 4);
        f2 = *(const float4*)(ear + 32);
        f3 = *(const float4*)(ear + 36);
    }
    __syncthreads();

    for (; tb < ntiles; tb += stride) {
        const int blockBase = tb * 64;

        // ---- Phase A: DMA xtile via global_load_lds (8 issues/wave) ----
        {
            const int rhalf = lane >> 5;    // 0/1
            const int cch   = lane & 31;    // 16B chunk in row
            char* ldsbase = (char*)tile + w * 8192;   // w*16 rows * 512B
#pragma unroll
            for (int i = 0; i < 8; i++) {
                int row = (w << 4) + (i << 1) + rhalf;
                int sid = smeta[bufc][0][row];
                const short* gp = xb + (long)sid * D + ((cch ^ (row & 7)) << 3);
                __builtin_amdgcn_global_load_lds(
                    (const __attribute__((address_space(1))) void*)gp,
                    (__attribute__((address_space(3))) void*)(ldsbase + (i << 10)),
                    16, 0, 0);
            }
        }

        // ---- B fragments for tile t from ea prefetched last iteration ----
        short8 b0 = pack8(f0, f1);   // B[k=q*8+j][n=edge], k-step 0
        short8 b1 = pack8(f2, f3);   // k-step 1

        // ---- meta(t+1) loads (into regs; written to LDS after bar1) ----
        int nsP = 0, ndP = -1;
        const long pnext = (long)(tb + stride) * 64;
        if (t < 64) {
            long p = pnext + t;
            long pc = (p < (long)E) ? p : (long)E - 1;
            nsP = srcP[pc];
            ndP = (p < (long)E) ? dstP[pc] : -1;
        }

        // bar1: full drain (DMA + meta complete). ea(t+1) not yet issued.
        __syncthreads();

        // ---- issue ea(t+1): stays in flight across bar2/bar3 ----
        {
            long ep = pnext + w * 16 + ln;
            if (ep >= (long)E) ep = (long)E - 1;
            int eid = perm[ep];
            const float* ear = ea + (long)eid * ED + q * 8;
            f0 = *(const float4*)(ear);
            f1 = *(const float4*)(ear + 4);
            f2 = *(const float4*)(ear + 32);
            f3 = *(const float4*)(ear + 36);
        }
        if (t < 64) {
            smeta[bufc ^ 1][0][t] = nsP;
            smeta[bufc ^ 1][1][t] = ndP;
        }

        // ---- MFMA + in-place epilogue: tile[edge][col] = relu(msg+be+x) ----
        const int erow = w * 16 + ln;
        const int swz = (erow & 7) << 4;
        char* rowp = (char*)tile + erow * 512;
#pragma unroll
        for (int mt = 0; mt < 16; mt++) {
            const short* wp = Wet + (mt * 16 + ln) * ED + q * 8;
            short8 a0 = *(const short8*)(wp);        // A[m=mt*16+ln][k=q*8+j]
            short8 a1 = *(const short8*)(wp + 32);
            f32x4 c = {0.f, 0.f, 0.f, 0.f};
            c = __builtin_amdgcn_mfma_f32_16x16x32_bf16(a0, b0, c, 0, 0, 0);
            c = __builtin_amdgcn_mfma_f32_16x16x32_bf16(a1, b1, c, 0, 0, 0);
            int colBase = mt * 16 + q * 4;
            char* ap = rowp + (((mt << 5) + (q << 3)) ^ swz);
            short4v xm = *(const short4v*)ap;          // ds_read_b64 (swizzled)
            f32x4 bev = *(const f32x4*)(be + colBase); // L1-hot global
            short4v o;
#pragma unroll
            for (int r = 0; r < 4; r++) {
                float v = fmaxf(c[r] + bev[r] + bf2f(xm[r]), 0.f);
                o[r] = bf16b(v);
            }
            *(short4v*)ap = o;                         // ds_write_b64 (swizzled)
        }

        // bar2: LDS-only barrier — does NOT drain vmcnt (ea stays in flight)
        lds_barrier();

        // ---- Phase D: segmented column scan; thread t owns column t ----
        {
            float s = 0.f;
            int curd = smeta[bufc][1][0];
#pragma unroll
            for (int row = 0; row < 64; row++) {
                int d = smeta[bufc][1][row];
                if (d != curd) {
                    if (curd >= 0) {
                        int gs = offs[curd], ge = offs[curd + 1];
                        float* ap = &aggr[(long)curd * D + t];
                        if (gs >= blockBase && ge <= blockBase + 64) *ap = s;
                        else unsafeAtomicAdd(ap, s);
                    }
                    curd = d;
                    s = 0.f;
                }
                short val = *(const short*)((const char*)tile + row * 512 +
                                            (((unsigned)t << 1) ^ ((row & 7) << 4)));
                s += bf2f(val);
            }
            if (curd >= 0) {
                int gs = offs[curd], ge = offs[curd + 1];
                float* ap = &aggr[(long)curd * D + t];
                if (gs >= blockBase && ge <= blockBase + 64) *ap = s;
                else unsafeAtomicAdd(ap, s);
            }
        }

        // bar3: LDS-only barrier — tile reads done before next DMA overwrite
        lds_barrier();
        bufc ^= 1;
    }
}

// ---------------- fused MLP + LN (z = x + aggr) ----------------
__global__ __launch_bounds__(256) void mlp_kernel(
    const float* __restrict__ x, const float* __restrict__ aggr,
    const short* __restrict__ W1t, const float* __restrict__ b1,
    const short* __restrict__ W2t, const float* __restrict__ b2,
    const float* __restrict__ gamma, const float* __restrict__ beta,
    float* __restrict__ out, int N) {
    __shared__ short tile[64][D + 8];
    const int t = threadIdx.x;
    const int rowBase = blockIdx.x * 64;

    {
        int c4 = t & 63;
        int r0 = t >> 6;
#pragma unroll
        for (int i = 0; i < 16; i++) {
            int row = i * 4 + r0;
            int grow = rowBase + row;
            int gr = grow < N ? grow : N - 1;
            float4 xv = *((const float4*)(x + (long)gr * D) + c4);
            float4 av = *((const float4*)(aggr + (long)gr * D) + c4);
            short4v sv;
            sv[0] = bf16b(xv.x + av.x);
            sv[1] = bf16b(xv.y + av.y);
            sv[2] = bf16b(xv.z + av.z);
            sv[3] = bf16b(xv.w + av.w);
            *(short4v*)&tile[row][c4 * 4] = sv;
        }
    }
    __syncthreads();

    const int lane = t & 63;
    const int w    = t >> 6;
    const int q    = lane >> 4;
    const int ln   = lane & 15;
    const int mrow = w * 16;

    f32x4 acc[16];
#pragma unroll
    for (int nt = 0; nt < 16; nt++) acc[nt] = (f32x4){0.f, 0.f, 0.f, 0.f};
#pragma unroll
    for (int s = 0; s < 8; s++) {
        int k = s * 32 + q * 8;
        short8 a = *(const short8*)&tile[mrow + ln][k];
#pragma unroll
        for (int nt = 0; nt < 16; nt++) {
            short8 b = *(const short8*)(W1t + (nt * 16 + ln) * D + k);
            acc[nt] = __builtin_amdgcn_mfma_f32_16x16x32_bf16(a, b, acc[nt], 0, 0, 0);
        }
    }

#pragma unroll
    for (int nt = 0; nt < 16; nt++) {
        int col = nt * 16 + ln;
        float bv = b1[col];
#pragma unroll
        for (int r = 0; r < 4; r++) {
            float v = fmaxf(acc[nt][r] + bv, 0.f);
            tile[mrow + q * 4 + r][col] = bf16b(v);
        }
    }

    f32x4 acc2[16];
#pragma unroll
    for (int nt = 0; nt < 16; nt++) acc2[nt] = (f32x4){0.f, 0.f, 0.f, 0.f};
#pragma unroll
    for (int s = 0; s < 8; s++) {
        int k = s * 32 + q * 8;
        short8 a = *(const short8*)&tile[mrow + ln][k];
#pragma unroll
        for (int nt = 0; nt < 16; nt++) {
            short8 b = *(const short8*)(W2t + (nt * 16 + ln) * D + k);
            acc2[nt] = __builtin_amdgcn_mfma_f32_16x16x32_bf16(a, b, acc2[nt], 0, 0, 0);
        }
    }

    float sum[4] = {0.f, 0.f, 0.f, 0.f};
    float sumsq[4] = {0.f, 0.f, 0.f, 0.f};
#pragma unroll
    for (int nt = 0; nt < 16; nt++) {
        int col = nt * 16 + ln;
        float b2v = b2[col];
#pragma unroll
        for (int r = 0; r < 4; r++) {
            int row = rowBase + mrow + q * 4 + r;
            int rc = row < N ? row : N - 1;
            float v = fmaxf(acc2[nt][r] + b2v, 0.f) + x[(long)rc * D + col];
            acc2[nt][r] = v;
            sum[r] += v;
            sumsq[r] += v * v;
        }
    }
#pragma unroll
    for (int m = 1; m <= 8; m <<= 1) {
#pragma unroll
        for (int r = 0; r < 4; r++) {
            sum[r]   += __shfl_xor(sum[r], m, 64);
            sumsq[r] += __shfl_xor(sumsq[r], m, 64);
        }
    }
    float mean[4], rstd[4];
#pragma unroll
    for (int r = 0; r < 4; r++) {
        mean[r] = sum[r] * (1.f / 256.f);
        float var = sumsq[r] * (1.f / 256.f) - mean[r] * mean[r];
        rstd[r] = rsqrtf(var + LN_EPS);
    }
#pragma unroll
    for (int nt = 0; nt < 16; nt++) {
        int col = nt * 16 + ln;
        float g = gamma[col], bb = beta[col];
#pragma unroll
        for (int r = 0; r < 4; r++) {
            int row = rowBase + mrow + q * 4 + r;
            if (row < N) {
                out[(long)row * D + col] = (acc2[nt][r] - mean[r]) * rstd[r] * g + bb;
            }
        }
    }
}

// ================= fallback path (round-1, atomics) =================
__global__ __launch_bounds__(256) void edge_kernel_v1(
    const float* __restrict__ ea, const int* __restrict__ src,
    const int* __restrict__ dst, const short* __restrict__ Wet,
    const float* __restrict__ be, const float* __restrict__ x,
    float* __restrict__ aggr, int E) {
    const int lane = threadIdx.x & 63;
    const int w    = threadIdx.x >> 6;
    const int q    = lane >> 4;
    const int ln   = lane & 15;
    const long eBase = (long)blockIdx.x * 64 + w * 16;
    long em = eBase + ln;
    if (em >= E) em = E - 1;
    const float* ear = ea + em * ED + q * 8;
    float4 f0 = *(const float4*)(ear);
    float4 f1 = *(const float4*)(ear + 4);
    float4 f2 = *(const float4*)(ear + 32);
    float4 f3 = *(const float4*)(ear + 36);
    short8 a0 = pack8(f0, f1);
    short8 a1 = pack8(f2, f3);
    f32x4 acc[16];
#pragma unroll
    for (int nt = 0; nt < 16; nt++) {
        const short* wp = Wet + (nt * 16 + ln) * ED + q * 8;
        short8 b0 = *(const short8*)(wp);
        short8 b1 = *(const short8*)(wp + 32);
        f32x4 c = {0.f, 0.f, 0.f, 0.f};
        c = __builtin_amdgcn_mfma_f32_16x16x32_bf16(a0, b0, c, 0, 0, 0);
        c = __builtin_amdgcn_mfma_f32_16x16x32_bf16(a1, b1, c, 0, 0, 0);
        acc[nt] = c;
    }
    int srcs[4], dsts[4];
    bool valid[4];
#pragma unroll
    for (int r = 0; r < 4; r++) {
        long e = eBase + q * 4 + r;
        valid[r] = (e < E);
        long ec = valid[r] ? e : 0;
        srcs[r] = src[ec];
        dsts[r] = dst[ec];
    }
#pragma unroll
    for (int nt = 0; nt < 16; nt++) {
        int col = nt * 16 + ln;
        float bev = be[col];
#pragma unroll
        for (int r = 0; r < 4; r++) {
            if (valid[r]) {
                float v = acc[nt][r] + bev + x[(long)srcs[r] * D + col];
                v = fmaxf(v, 0.f);
                unsafeAtomicAdd(&aggr[(long)dsts[r] * D + col], v);
            }
        }
    }
}

// ================= host =================
extern "C" void kernel_launch(void* const* d_in, const int* in_sizes, int n_in,
                              void* d_out, int out_size, void* d_ws, size_t ws_size,
                              hipStream_t stream) {
    const float* x     = (const float*)d_in[0];
    const int*   ei    = (const int*)d_in[1];
    const float* ea    = (const float*)d_in[2];
    const float* We    = (const float*)d_in[3];
    const float* be    = (const float*)d_in[4];
    const float* W1    = (const float*)d_in[5];
    const float* b1    = (const float*)d_in[6];
    const float* W2    = (const float*)d_in[7];
    const float* b2    = (const float*)d_in[8];
    const float* gamma = (const float*)d_in[9];
    const float* beta  = (const float*)d_in[10];

    const int N = in_sizes[0] / D;
    const int E = in_sizes[1] / 2;
    const int* src = ei;
    const int* dst = ei + E;

    char* ws = (char*)d_ws;
    size_t off = 0;
    auto alloc = [&](size_t bytes) -> size_t {
        size_t o = off;
        off = (off + bytes + 255) & ~(size_t)255;
        return o;
    };
    size_t o_offs   = alloc((size_t)(N + 1) * 4);
    size_t o_counts = alloc((size_t)(N + 1) * 4);
    size_t o_cursor = alloc((size_t)N * 4);
    size_t o_bsum   = alloc(256 * 4);
    size_t o_bofs   = alloc(256 * 4);
    size_t o_perm   = alloc((size_t)E * 4);
    size_t o_srcP   = alloc((size_t)E * 4);
    size_t o_dstP   = alloc((size_t)E * 4);
    size_t o_Wet    = alloc((size_t)D * ED * 2);
    size_t o_W1t    = alloc((size_t)D * D * 2);
    size_t o_W2t    = alloc((size_t)D * D * 2);
    size_t o_xb     = alloc((size_t)N * D * 2);
    size_t o_aggr   = alloc((size_t)N * D * 4);
    size_t need = off;

    if (ws_size >= need) {
        int*   offs   = (int*)(ws + o_offs);
        int*   counts = (int*)(ws + o_counts);
        int*   cursor = (int*)(ws + o_cursor);
        int*   bsum   = (int*)(ws + o_bsum);
        int*   bofs   = (int*)(ws + o_bofs);
        int*   perm   = (int*)(ws + o_perm);
        int*   srcP   = (int*)(ws + o_srcP);
        int*   dstP   = (int*)(ws + o_dstP);
        short* Wet    = (short*)(ws + o_Wet);
        short* W1t    = (short*)(ws + o_W1t);
        short* W2t    = (short*)(ws + o_W2t);
        short* xb     = (short*)(ws + o_xb);
        float* aggr   = (float*)(ws + o_aggr);

        hipMemsetAsync(counts, 0, (size_t)(N + 1) * 4, stream);
        hipMemsetAsync(aggr, 0, (size_t)N * D * 4, stream);
        prep_weights<<<dim3(256), dim3(256), 0, stream>>>(We, W1, W2, Wet, W1t, W2t);
        int n4 = N * D / 4;
        cast_x<<<dim3((n4 + 255) / 256), dim3(256), 0, stream>>>(x, xb, n4);

        hist_kernel<<<dim3((E + 255) / 256), dim3(256), 0, stream>>>(dst, counts, E);
        int nscan = N + 1;
        int nb = (nscan + 255) / 256;
        scan_block<<<dim3(nb), dim3(256), 0, stream>>>(counts, offs, bsum, nscan);
        scan_block<<<dim3(1), dim3(256), 0, stream>>>(bsum, bofs, (int*)nullptr, nb);
        scan_add<<<dim3(nb), dim3(256), 0, stream>>>(offs, bofs, cursor, nscan, N);
        scatter_edges<<<dim3((E + 255) / 256), dim3(256), 0, stream>>>(
            src, dst, cursor, perm, srcP, dstP, E);

        int ntiles = (E + 63) / 64;
        int nblk = ntiles < 1024 ? ntiles : 1024;
        fused_edge<<<dim3(nblk), dim3(256), 0, stream>>>(
            ea, perm, srcP, dstP, offs, Wet, be, xb, aggr, E, ntiles);
        mlp_kernel<<<dim3((N + 63) / 64), dim3(256), 0, stream>>>(
            x, aggr, W1t, b1, W2t, b2, gamma, beta, (float*)d_out, N);
    } else {
        float* aggr = (float*)ws;
        size_t aggrB = (size_t)N * D * sizeof(float);
        short* Wet = (short*)(ws + aggrB);
        short* W1t = Wet + D * ED;
        short* W2t = W1t + D * D;

        hipMemsetAsync(aggr, 0, aggrB, stream);
        prep_weights<<<dim3(256), dim3(256), 0, stream>>>(We, W1, W2, Wet, W1t, W2t);
        edge_kernel_v1<<<dim3((E + 63) / 64), dim3(256), 0, stream>>>(ea, src, dst, Wet, be, x, aggr, E);
        mlp_kernel<<<dim3((N + 63) / 64), dim3(256), 0, stream>>>(
            x, aggr, W1t, b1, W2t, b2, gamma, beta, (float*)d_out, N);
    }
}